// Round 3
// baseline (483.905 us; speedup 1.0000x reference)
//
#include <hip/hip_runtime.h>
#include <hip/hip_bf16.h>
#include <math.h>

#define HIDDEN 1024
#define HEADS 16
#define HEAD_DIM 64
#define POS_DIM 128
#define BATCH 2
#define SEQ 2048
#define TOKENS (BATCH * SEQ)

typedef _Float16 f16;
typedef __attribute__((ext_vector_type(8))) _Float16 f16x8;
typedef __attribute__((ext_vector_type(4))) _Float16 f16x4;
typedef __attribute__((ext_vector_type(4))) float f32x4;

// ---------------------------------------------------------------------------
// cast x (fp32 -> f16), 8 elems/thread
// ---------------------------------------------------------------------------
__global__ __launch_bounds__(256) void cast_x_kernel(const float* __restrict__ x,
                                                     f16* __restrict__ o) {
    const int i = (blockIdx.x * 256 + threadIdx.x) * 8;
    const float4 u = *(const float4*)(x + i);
    const float4 v = *(const float4*)(x + i + 4);
    f16x8 r = {(f16)u.x, (f16)u.y, (f16)u.z, (f16)u.w,
               (f16)v.x, (f16)v.y, (f16)v.z, (f16)v.w};
    *(f16x8*)(o + i) = r;
}

// ---------------------------------------------------------------------------
// W [1024][1024] fp32 -> Wt [1024][1024] f16 (transpose), 32x32 tiles
// ---------------------------------------------------------------------------
__global__ __launch_bounds__(256) void cast_wt_kernel(const float* __restrict__ W,
                                                      f16* __restrict__ Wt) {
    __shared__ float ts[32][33];
    const int t = threadIdx.x;
    const int k0 = blockIdx.y * 32, n0 = blockIdx.x * 32;
    {
        const int r = t >> 3, c4 = (t & 7) * 4;
        const float4 u = *(const float4*)(W + (size_t)(k0 + r) * HIDDEN + n0 + c4);
        ts[r][c4 + 0] = u.x; ts[r][c4 + 1] = u.y; ts[r][c4 + 2] = u.z; ts[r][c4 + 3] = u.w;
    }
    __syncthreads();
    {
        const int r = t >> 3, c4 = (t & 7) * 4;
        f16* o = Wt + (size_t)(n0 + r) * HIDDEN + k0 + c4;
        o[0] = (f16)ts[c4 + 0][r]; o[1] = (f16)ts[c4 + 1][r];
        o[2] = (f16)ts[c4 + 2][r]; o[3] = (f16)ts[c4 + 3][r];
    }
}

// ---------------------------------------------------------------------------
// Fused QKV GEMM: C[4096][3072] = A[4096][1024] @ Bt[3072][1024]^T, f16 out.
// Block tile 64M x 256N (4 waves 1x4, A-frags shared -> L1 reuse), 64x64/wave.
// grid (12, 64) = 768 blocks = 3 blocks/CU.
// ---------------------------------------------------------------------------
__global__ __launch_bounds__(256, 3) void gemm_qkv(const f16* __restrict__ A,
                                                   const f16* __restrict__ Bt,
                                                   f16* __restrict__ C) {
    const int tid = threadIdx.x;
    const int w = tid >> 6, lane = tid & 63;
    const int g = lane >> 4, c = lane & 15;
    const int m0 = blockIdx.y * 64;
    const int n0 = blockIdx.x * 256 + w * 64;

    const f16* Ab = A + (size_t)m0 * HIDDEN + g * 8;
    const f16* Bb = Bt + (size_t)n0 * HIDDEN + g * 8;

    f32x4 acc[4][4];
    const f32x4 z = {0.f, 0.f, 0.f, 0.f};
#pragma unroll
    for (int i = 0; i < 4; ++i)
#pragma unroll
        for (int j = 0; j < 4; ++j) acc[i][j] = z;

    f16x8 a0[4], b0[4], a1[4], b1[4];
#pragma unroll
    for (int i = 0; i < 4; ++i) {
        a0[i] = *(const f16x8*)(Ab + (size_t)(i * 16 + c) * HIDDEN);
        b0[i] = *(const f16x8*)(Bb + (size_t)(i * 16 + c) * HIDDEN);
    }
    for (int k0 = 0; k0 < HIDDEN; k0 += 64) {
        const int kp1 = k0 + 32;
        const int kp2 = (k0 + 64) & (HIDDEN - 1);
#pragma unroll
        for (int i = 0; i < 4; ++i) {
            a1[i] = *(const f16x8*)(Ab + (size_t)(i * 16 + c) * HIDDEN + kp1);
            b1[i] = *(const f16x8*)(Bb + (size_t)(i * 16 + c) * HIDDEN + kp1);
        }
#pragma unroll
        for (int i = 0; i < 4; ++i)
#pragma unroll
            for (int j = 0; j < 4; ++j)
                acc[i][j] = __builtin_amdgcn_mfma_f32_16x16x32_f16(a0[i], b0[j], acc[i][j], 0, 0, 0);
#pragma unroll
        for (int i = 0; i < 4; ++i) {
            a0[i] = *(const f16x8*)(Ab + (size_t)(i * 16 + c) * HIDDEN + kp2);
            b0[i] = *(const f16x8*)(Bb + (size_t)(i * 16 + c) * HIDDEN + kp2);
        }
#pragma unroll
        for (int i = 0; i < 4; ++i)
#pragma unroll
            for (int j = 0; j < 4; ++j)
                acc[i][j] = __builtin_amdgcn_mfma_f32_16x16x32_f16(a1[i], b1[j], acc[i][j], 0, 0, 0);
    }
#pragma unroll
    for (int i = 0; i < 4; ++i)
#pragma unroll
        for (int j = 0; j < 4; ++j)
#pragma unroll
            for (int r = 0; r < 4; ++r)
                C[(size_t)(m0 + i * 16 + 4 * g + r) * 3072 + n0 + j * 16 + c] = (f16)acc[i][j][r];
}

// ---------------------------------------------------------------------------
// Output GEMM: C[4096][1024] fp32 = A[4096][1024]f16 @ Bt[1024][1024]^T.
// Block 64M x 128N (4 waves 1x4), 64x32/wave. grid (8, 64) = 512 blocks.
// ---------------------------------------------------------------------------
__global__ __launch_bounds__(256) void gemm_wo(const f16* __restrict__ A,
                                               const f16* __restrict__ Bt,
                                               float* __restrict__ C) {
    const int tid = threadIdx.x;
    const int w = tid >> 6, lane = tid & 63;
    const int g = lane >> 4, c = lane & 15;
    const int m0 = blockIdx.y * 64;
    const int n0 = blockIdx.x * 128 + w * 32;

    const f16* Ab = A + (size_t)m0 * HIDDEN + g * 8;
    const f16* Bb = Bt + (size_t)n0 * HIDDEN + g * 8;

    f32x4 acc[4][2];
    const f32x4 z = {0.f, 0.f, 0.f, 0.f};
#pragma unroll
    for (int i = 0; i < 4; ++i) { acc[i][0] = z; acc[i][1] = z; }

    f16x8 a0[4], b0[2], a1[4], b1[2];
#pragma unroll
    for (int i = 0; i < 4; ++i) a0[i] = *(const f16x8*)(Ab + (size_t)(i * 16 + c) * HIDDEN);
#pragma unroll
    for (int j = 0; j < 2; ++j) b0[j] = *(const f16x8*)(Bb + (size_t)(j * 16 + c) * HIDDEN);

    for (int k0 = 0; k0 < HIDDEN; k0 += 64) {
        const int kp1 = k0 + 32;
        const int kp2 = (k0 + 64) & (HIDDEN - 1);
#pragma unroll
        for (int i = 0; i < 4; ++i) a1[i] = *(const f16x8*)(Ab + (size_t)(i * 16 + c) * HIDDEN + kp1);
#pragma unroll
        for (int j = 0; j < 2; ++j) b1[j] = *(const f16x8*)(Bb + (size_t)(j * 16 + c) * HIDDEN + kp1);
#pragma unroll
        for (int i = 0; i < 4; ++i)
#pragma unroll
            for (int j = 0; j < 2; ++j)
                acc[i][j] = __builtin_amdgcn_mfma_f32_16x16x32_f16(a0[i], b0[j], acc[i][j], 0, 0, 0);
#pragma unroll
        for (int i = 0; i < 4; ++i) a0[i] = *(const f16x8*)(Ab + (size_t)(i * 16 + c) * HIDDEN + kp2);
#pragma unroll
        for (int j = 0; j < 2; ++j) b0[j] = *(const f16x8*)(Bb + (size_t)(j * 16 + c) * HIDDEN + kp2);
#pragma unroll
        for (int i = 0; i < 4; ++i)
#pragma unroll
            for (int j = 0; j < 2; ++j)
                acc[i][j] = __builtin_amdgcn_mfma_f32_16x16x32_f16(a1[i], b1[j], acc[i][j], 0, 0, 0);
    }
#pragma unroll
    for (int i = 0; i < 4; ++i)
#pragma unroll
        for (int j = 0; j < 2; ++j)
#pragma unroll
            for (int r = 0; r < 4; ++r)
                C[(size_t)(m0 + i * 16 + 4 * g + r) * HIDDEN + n0 + j * 16 + c] = acc[i][j][r];
}

// ---------------------------------------------------------------------------
// RePo MLP, fp32, 8 tokens/block
// ---------------------------------------------------------------------------
__device__ __forceinline__ float gelu_tanh(float x) {
    const float kA = 0.7978845608028654f;
    return 0.5f * x * (1.0f + tanhf(kA * (x + 0.044715f * x * x * x)));
}

__global__ __launch_bounds__(128) void repo_raw_kernel(const float* __restrict__ x,
                                                       const float* __restrict__ W1,
                                                       const float* __restrict__ b1,
                                                       const float* __restrict__ W2,
                                                       const float* __restrict__ b2,
                                                       float* __restrict__ raw) {
    __shared__ float xs[8 * HIDDEN];
    __shared__ float red[8][2];
    const int tid = threadIdx.x;
    const int tok0 = blockIdx.x * 8;
    const float* xb = x + (size_t)tok0 * HIDDEN;

#pragma unroll
    for (int i = 0; i < 64; ++i) xs[i * 128 + tid] = xb[i * 128 + tid];
    __syncthreads();

    float acc[8] = {};
    const float* w1p = W1 + tid;
#pragma unroll 8
    for (int d = 0; d < HIDDEN; ++d) {
        const float wv = w1p[d * POS_DIM];
#pragma unroll
        for (int j = 0; j < 8; ++j) acc[j] += xs[j * HIDDEN + d] * wv;
    }
    const float b1v = b1[tid];
    const float w2v = W2[tid];
    float cv[8];
#pragma unroll
    for (int j = 0; j < 8; ++j) cv[j] = gelu_tanh(acc[j] + b1v) * w2v;

#pragma unroll
    for (int off = 1; off < 64; off <<= 1)
#pragma unroll
        for (int j = 0; j < 8; ++j) cv[j] += __shfl_xor(cv[j], off, 64);

    const int wave = tid >> 6;
    if ((tid & 63) == 0)
        for (int j = 0; j < 8; ++j) red[j][wave] = cv[j];
    __syncthreads();
    if (tid == 0) {
        const float b2v = b2[0];
        for (int j = 0; j < 8; ++j) raw[tok0 + j] = red[j][0] + red[j][1] + b2v;
    }
}

__device__ __forceinline__ double softplus_d(double x) {
    return (x > 0.0) ? x + log1p(exp(-x)) : log1p(exp(x));
}

__global__ __launch_bounds__(256) void repo_cumsum_kernel(const float* __restrict__ raw,
                                                          float* __restrict__ pos) {
    __shared__ double bufA[256];
    __shared__ double bufB[256];
    const int b = blockIdx.x;
    const int t = threadIdx.x;
    const float* r = raw + (size_t)b * SEQ;

    double loc[8];
    double sum = 0.0;
#pragma unroll
    for (int i = 0; i < 8; ++i) {
        sum += softplus_d((double)r[t * 8 + i]);
        loc[i] = sum;
    }
    bufA[t] = sum;
    __syncthreads();

    double* src = bufA;
    double* dst = bufB;
    for (int off = 1; off < 256; off <<= 1) {
        double v = src[t];
        if (t >= off) v += src[t - off];
        dst[t] = v;
        __syncthreads();
        double* tmp = src; src = dst; dst = tmp;
    }
    const double excl = src[t] - sum;
#pragma unroll
    for (int i = 0; i < 8; ++i)
        pos[(size_t)b * SEQ + t * 8 + i] = (float)(excl + loc[i]);
}

// ---------------------------------------------------------------------------
// RoPE in-place on fused qkv (f16, row stride 3072)
// ---------------------------------------------------------------------------
__global__ __launch_bounds__(256) void rope_kernel(f16* __restrict__ qkv,
                                                   const float* __restrict__ pos) {
    const int gi = blockIdx.x * 256 + threadIdx.x;
    const int i = gi & 31;
    const int h = (gi >> 5) & (HEADS - 1);
    const int tok = gi >> 9;
    const double ang = (double)pos[tok] * exp(-(double)i * 0.28782313662425574);
    double sa, ca;
    sincos(ang, &sa, &ca);
    const float cf = (float)ca, sf = (float)sa;
    const size_t base = (size_t)tok * 3072 + h * HEAD_DIM + i;
    const float q1 = (float)qkv[base], q2 = (float)qkv[base + 32];
    qkv[base]      = (f16)(q1 * cf - q2 * sf);
    qkv[base + 32] = (f16)(q1 * sf + q2 * cf);
    const size_t kb = base + 1024;
    const float k1 = (float)qkv[kb], k2 = (float)qkv[kb + 32];
    qkv[kb]      = (f16)(k1 * cf - k2 * sf);
    qkv[kb + 32] = (f16)(k1 * sf + k2 * cf);
}

// ---------------------------------------------------------------------------
// V (in qkv, stride 3072) -> Vt [(b*16+h)*64 + d][s]
// ---------------------------------------------------------------------------
__global__ __launch_bounds__(256) void vtrans_kernel(const f16* __restrict__ qkv,
                                                     f16* __restrict__ vt) {
    __shared__ __align__(16) f16 ts[64][72];
    const int t = threadIdx.x;
    const int s0 = blockIdx.x * 64;
    const int h = blockIdx.y, b = blockIdx.z;
    const f16* v = qkv + 2048;
#pragma unroll
    for (int p = 0; p < 2; ++p) {
        const int sl = (t >> 3) + p * 32;
        const int dc = (t & 7) * 8;
        f16x8 u = *(const f16x8*)(v + (size_t)(b * SEQ + s0 + sl) * 3072 + h * HEAD_DIM + dc);
#pragma unroll
        for (int uu = 0; uu < 8; ++uu) ts[dc + uu][sl] = u[uu];
    }
    __syncthreads();
    f16* o = vt + (size_t)((b * HEADS + h) * HEAD_DIM) * SEQ;
#pragma unroll
    for (int p = 0; p < 2; ++p) {
        const int qq = t + 256 * p;
        const int d = qq >> 3;
        const int cc = (qq & 7) * 8;
        *(f16x8*)(o + (size_t)d * SEQ + s0 + cc) = *(const f16x8*)(&ts[d][cc]);
    }
}

// ---------------------------------------------------------------------------
// MFMA flash attention, f16, zero-LDS K-loop.
// Role-swapped QK^T (S^T in C-layout == B-frag of 16x16x16) -> P stays in regs.
// 32 q-rows/wave, 4 waves/block, grid (16,16,2)=512 blocks (2 blocks/CU).
// Fixed-shift softmax (2^(s*scale*log2e - 8)); denominators via ones-MFMA.
// ---------------------------------------------------------------------------
__global__ __launch_bounds__(256) void attn_f16(const f16* __restrict__ qkv,
                                                const f16* __restrict__ vt,
                                                f16* __restrict__ ao) {
    __shared__ __align__(16) f16 ot[4][32][72];
    const int tid = threadIdx.x;
    const int w = tid >> 6, lane = tid & 63;
    const int g = lane >> 4, c = lane & 15;
    const int h = blockIdx.y, b = blockIdx.z;
    const int row0 = blockIdx.x * 128 + w * 32;

    const f16* qb = qkv + (size_t)(b * SEQ + row0) * 3072 + h * HEAD_DIM + g * 8;
    const f16* kb = qkv + (size_t)b * SEQ * 3072 + 1024 + h * HEAD_DIM + g * 8;
    const f16* vb = vt + (size_t)((b * HEADS + h) * HEAD_DIM) * SEQ;

    f16x8 qf[2][2];
#pragma unroll
    for (int i = 0; i < 2; ++i) {
        qf[i][0] = *(const f16x8*)(qb + (size_t)(i * 16 + c) * 3072);
        qf[i][1] = *(const f16x8*)(qb + (size_t)(i * 16 + c) * 3072 + 32);
    }
    const f32x4 z = {0.f, 0.f, 0.f, 0.f};
    f32x4 acc[4][2];   // [dim-tile jd][qrow-tile i] of O^T
    f32x4 accl[2];     // softmax denominators (replicated over m)
#pragma unroll
    for (int jd = 0; jd < 4; ++jd) { acc[jd][0] = z; acc[jd][1] = z; }
    accl[0] = z; accl[1] = z;

    const f16x4 ones = {(f16)1.f, (f16)1.f, (f16)1.f, (f16)1.f};
    const float SC = 0.125f * 1.4426950408889634f;

    for (int c0 = 0; c0 < SEQ; c0 += 64) {
        f16x8 kf[4][2];
#pragma unroll
        for (int jn = 0; jn < 4; ++jn) {
            kf[jn][0] = *(const f16x8*)(kb + (size_t)(c0 + jn * 16 + c) * 3072);
            kf[jn][1] = *(const f16x8*)(kb + (size_t)(c0 + jn * 16 + c) * 3072 + 32);
        }
        f16x4 vf[4][4];  // [jd][jn]: V^T[dim jd*16+c][keys c0+jn*16+4g..+3]
#pragma unroll
        for (int jd = 0; jd < 4; ++jd)
#pragma unroll
            for (int jn = 0; jn < 4; ++jn)
                vf[jd][jn] = *(const f16x4*)(vb + (size_t)(jd * 16 + c) * SEQ + c0 + jn * 16 + 4 * g);

#pragma unroll
        for (int i = 0; i < 2; ++i) {
            f32x4 s[4];
#pragma unroll
            for (int jn = 0; jn < 4; ++jn) {
                s[jn] = __builtin_amdgcn_mfma_f32_16x16x32_f16(kf[jn][0], qf[i][0], z, 0, 0, 0);
                s[jn] = __builtin_amdgcn_mfma_f32_16x16x32_f16(kf[jn][1], qf[i][1], s[jn], 0, 0, 0);
            }
#pragma unroll
            for (int jn = 0; jn < 4; ++jn) {
                f16x4 pf;
#pragma unroll
                for (int r = 0; r < 4; ++r)
                    pf[r] = (f16)__builtin_amdgcn_exp2f(fmaf(s[jn][r], SC, -8.0f));
                accl[i] = __builtin_amdgcn_mfma_f32_16x16x16f16(ones, pf, accl[i], 0, 0, 0);
#pragma unroll
                for (int jd = 0; jd < 4; ++jd)
                    acc[jd][i] = __builtin_amdgcn_mfma_f32_16x16x16f16(vf[jd][jn], pf, acc[jd][i], 0, 0, 0);
            }
        }
    }
    // epilogue: O^T[dim][qrow] in regs -> LDS transpose (wave-private) -> coalesced store
#pragma unroll
    for (int i = 0; i < 2; ++i) {
        const float inv = 1.0f / accl[i][0];
#pragma unroll
        for (int jd = 0; jd < 4; ++jd)
#pragma unroll
            for (int r = 0; r < 4; ++r)
                ot[w][i * 16 + c][jd * 16 + 4 * g + r] = (f16)(acc[jd][i][r] * inv);
    }
    const int t = lane >> 1, hf = lane & 1;
    f16* aob = ao + (size_t)(b * SEQ + row0 + t) * HIDDEN + h * HEAD_DIM + hf * 32;
#pragma unroll
    for (int q = 0; q < 4; ++q)
        *(f16x8*)(aob + q * 8) = *(const f16x8*)(&ot[w][t][hf * 32 + q * 8]);
}

// ---------------------------------------------------------------------------
// launch
// ---------------------------------------------------------------------------
extern "C" void kernel_launch(void* const* d_in, const int* in_sizes, int n_in,
                              void* d_out, int out_size, void* d_ws, size_t ws_size,
                              hipStream_t stream) {
    const float* x   = (const float*)d_in[0];
    const float* W_q = (const float*)d_in[1];
    const float* W_k = (const float*)d_in[2];
    const float* W_v = (const float*)d_in[3];
    const float* W_o = (const float*)d_in[4];
    const float* rW1 = (const float*)d_in[5];
    const float* rb1 = (const float*)d_in[6];
    const float* rW2 = (const float*)d_in[7];
    const float* rb2 = (const float*)d_in[8];
    float* out = (float*)d_out;

    const size_t MAT = (size_t)TOKENS * HIDDEN;   // 4M
    const size_t WSZ = (size_t)HIDDEN * HIDDEN;   // 1M
    f16* x16  = (f16*)d_ws;
    f16* wqkv = x16 + MAT;            // [3072][1024]
    f16* wot  = wqkv + 3 * WSZ;
    f16* qkv  = wot + WSZ;            // [4096][3072]
    f16* vt   = qkv + 3 * MAT;
    f16* aof  = vt + MAT;
    float* raw = (float*)(aof + MAT);
    float* pos = raw + TOKENS;

    cast_x_kernel<<<MAT / 2048, 256, 0, stream>>>(x, x16);
    cast_wt_kernel<<<dim3(32, 32), 256, 0, stream>>>(W_q, wqkv);
    cast_wt_kernel<<<dim3(32, 32), 256, 0, stream>>>(W_k, wqkv + WSZ);
    cast_wt_kernel<<<dim3(32, 32), 256, 0, stream>>>(W_v, wqkv + 2 * WSZ);
    cast_wt_kernel<<<dim3(32, 32), 256, 0, stream>>>(W_o, wot);

    gemm_qkv<<<dim3(12, 64), 256, 0, stream>>>(x16, wqkv, qkv);

    repo_raw_kernel<<<TOKENS / 8, 128, 0, stream>>>(x, rW1, rb1, rW2, rb2, raw);
    repo_cumsum_kernel<<<BATCH, 256, 0, stream>>>(raw, pos);

    rope_kernel<<<(TOKENS * HEADS * 32) / 256, 256, 0, stream>>>(qkv, pos);
    vtrans_kernel<<<dim3(SEQ / 64, HEADS, BATCH), 256, 0, stream>>>(qkv, vt);

    attn_f16<<<dim3(SEQ / 128, HEADS, BATCH), 256, 0, stream>>>(qkv, vt, aof);

    gemm_wo<<<dim3(8, 64), 256, 0, stream>>>(aof, wot, out);
}

// Round 4
// 291.071 us; speedup vs baseline: 1.6625x; 1.6625x over previous
//
#include <hip/hip_runtime.h>
#include <hip/hip_bf16.h>
#include <math.h>

#define HIDDEN 1024
#define HEADS 16
#define HEAD_DIM 64
#define POS_DIM 128
#define BATCH 2
#define SEQ 2048
#define TOKENS (BATCH * SEQ)

typedef _Float16 f16;
typedef __attribute__((ext_vector_type(8))) _Float16 f16x8;
typedef __attribute__((ext_vector_type(4))) _Float16 f16x4;
typedef __attribute__((ext_vector_type(4))) float f32x4;

// ---------------------------------------------------------------------------
// cast x (fp32 -> f16), 8 elems/thread
// ---------------------------------------------------------------------------
__global__ __launch_bounds__(256) void cast_x_kernel(const float* __restrict__ x,
                                                     f16* __restrict__ o) {
    const int i = (blockIdx.x * 256 + threadIdx.x) * 8;
    const float4 u = *(const float4*)(x + i);
    const float4 v = *(const float4*)(x + i + 4);
    f16x8 r = {(f16)u.x, (f16)u.y, (f16)u.z, (f16)u.w,
               (f16)v.x, (f16)v.y, (f16)v.z, (f16)v.w};
    *(f16x8*)(o + i) = r;
}

// ---------------------------------------------------------------------------
// W [1024][1024] fp32 -> Wt [1024][1024] f16 (transpose), 32x32 tiles
// ---------------------------------------------------------------------------
__global__ __launch_bounds__(256) void cast_wt_kernel(const float* __restrict__ W,
                                                      f16* __restrict__ Wt) {
    __shared__ float ts[32][33];
    const int t = threadIdx.x;
    const int k0 = blockIdx.y * 32, n0 = blockIdx.x * 32;
    {
        const int r = t >> 3, c4 = (t & 7) * 4;
        const float4 u = *(const float4*)(W + (size_t)(k0 + r) * HIDDEN + n0 + c4);
        ts[r][c4 + 0] = u.x; ts[r][c4 + 1] = u.y; ts[r][c4 + 2] = u.z; ts[r][c4 + 3] = u.w;
    }
    __syncthreads();
    {
        const int r = t >> 3, c4 = (t & 7) * 4;
        f16* o = Wt + (size_t)(n0 + r) * HIDDEN + k0 + c4;
        o[0] = (f16)ts[c4 + 0][r]; o[1] = (f16)ts[c4 + 1][r];
        o[2] = (f16)ts[c4 + 2][r]; o[3] = (f16)ts[c4 + 3][r];
    }
}

// ---------------------------------------------------------------------------
// LDS-staged f16 MFMA GEMM: C[4096][N] = A[4096][1024] @ Bt[N][1024]^T.
// 128x128 block tile, BK=32, 4 waves 2x2 (64x64 each). XOR-swizzled LDS
// (2-way max conflicts), register prefetch of next K-slab.
// ---------------------------------------------------------------------------
__global__ __launch_bounds__(256, 2) void gemm_lds(const f16* __restrict__ A,
                                                   const f16* __restrict__ Bt,
                                                   f16* __restrict__ Cb,
                                                   float* __restrict__ Cf,
                                                   int N, int f16out) {
    __shared__ __align__(16) f16 As[128 * 32];
    __shared__ __align__(16) f16 Bs[128 * 32];
    const int tid = threadIdx.x;
    const int w = tid >> 6, lane = tid & 63;
    const int g = lane >> 4, c = lane & 15;
    const int m0 = blockIdx.y * 128, n0 = blockIdx.x * 128;
    const int wm = (w & 1) * 64, wn = (w >> 1) * 64;

    // staging: thread covers rows srow and srow+64, 16B chunk sseg, swizzled slot
    const int srow = tid >> 2, sseg = tid & 3;
    const int slot = (sseg ^ ((srow ^ (srow >> 2)) & 3)) << 3;
    const f16* gA = A + (size_t)(m0 + srow) * 1024 + sseg * 8;
    const f16* gB = Bt + (size_t)(n0 + srow) * 1024 + sseg * 8;
    f16* sA0 = &As[srow * 32 + slot];
    f16* sA1 = &As[(srow + 64) * 32 + slot];
    f16* sB0 = &Bs[srow * 32 + slot];
    f16* sB1 = &Bs[(srow + 64) * 32 + slot];

    const int foff = ((g ^ ((c ^ (c >> 2)) & 3)) << 3);  // frag-read swizzle

    f32x4 acc[4][4];
    const f32x4 z = {0.f, 0.f, 0.f, 0.f};
#pragma unroll
    for (int i = 0; i < 4; ++i)
#pragma unroll
        for (int j = 0; j < 4; ++j) acc[i][j] = z;

    f16x8 pA0 = *(const f16x8*)gA;
    f16x8 pA1 = *(const f16x8*)(gA + 64 * 1024);
    f16x8 pB0 = *(const f16x8*)gB;
    f16x8 pB1 = *(const f16x8*)(gB + 64 * 1024);

    for (int k0 = 0; k0 < 1024; k0 += 32) {
        __syncthreads();   // prior iteration's frag reads done
        *(f16x8*)sA0 = pA0; *(f16x8*)sA1 = pA1;
        *(f16x8*)sB0 = pB0; *(f16x8*)sB1 = pB1;
        __syncthreads();   // tile visible
        if (k0 + 32 < 1024) {
            pA0 = *(const f16x8*)(gA + k0 + 32);
            pA1 = *(const f16x8*)(gA + 64 * 1024 + k0 + 32);
            pB0 = *(const f16x8*)(gB + k0 + 32);
            pB1 = *(const f16x8*)(gB + 64 * 1024 + k0 + 32);
        }
        f16x8 af[4], bf[4];
#pragma unroll
        for (int i = 0; i < 4; ++i)
            af[i] = *(const f16x8*)&As[(wm + i * 16 + c) * 32 + foff];
#pragma unroll
        for (int j = 0; j < 4; ++j)
            bf[j] = *(const f16x8*)&Bs[(wn + j * 16 + c) * 32 + foff];
#pragma unroll
        for (int i = 0; i < 4; ++i)
#pragma unroll
            for (int j = 0; j < 4; ++j)
                acc[i][j] = __builtin_amdgcn_mfma_f32_16x16x32_f16(af[i], bf[j], acc[i][j], 0, 0, 0);
    }
#pragma unroll
    for (int i = 0; i < 4; ++i)
#pragma unroll
        for (int j = 0; j < 4; ++j)
#pragma unroll
            for (int r = 0; r < 4; ++r) {
                const size_t off = (size_t)(m0 + wm + i * 16 + 4 * g + r) * N + n0 + wn + j * 16 + c;
                if (f16out) Cb[off] = (f16)acc[i][j][r];
                else Cf[off] = acc[i][j][r];
            }
}

// ---------------------------------------------------------------------------
// RePo MLP, fp32, 8 tokens/block
// ---------------------------------------------------------------------------
__device__ __forceinline__ float gelu_tanh(float x) {
    const float kA = 0.7978845608028654f;
    return 0.5f * x * (1.0f + tanhf(kA * (x + 0.044715f * x * x * x)));
}

__global__ __launch_bounds__(128) void repo_raw_kernel(const float* __restrict__ x,
                                                       const float* __restrict__ W1,
                                                       const float* __restrict__ b1,
                                                       const float* __restrict__ W2,
                                                       const float* __restrict__ b2,
                                                       float* __restrict__ raw) {
    __shared__ float xs[8 * HIDDEN];
    __shared__ float red[8][2];
    const int tid = threadIdx.x;
    const int tok0 = blockIdx.x * 8;
    const float* xb = x + (size_t)tok0 * HIDDEN;

#pragma unroll
    for (int i = 0; i < 64; ++i) xs[i * 128 + tid] = xb[i * 128 + tid];
    __syncthreads();

    float acc[8] = {};
    const float* w1p = W1 + tid;
#pragma unroll 8
    for (int d = 0; d < HIDDEN; ++d) {
        const float wv = w1p[d * POS_DIM];
#pragma unroll
        for (int j = 0; j < 8; ++j) acc[j] += xs[j * HIDDEN + d] * wv;
    }
    const float b1v = b1[tid];
    const float w2v = W2[tid];
    float cv[8];
#pragma unroll
    for (int j = 0; j < 8; ++j) cv[j] = gelu_tanh(acc[j] + b1v) * w2v;

#pragma unroll
    for (int off = 1; off < 64; off <<= 1)
#pragma unroll
        for (int j = 0; j < 8; ++j) cv[j] += __shfl_xor(cv[j], off, 64);

    const int wave = tid >> 6;
    if ((tid & 63) == 0)
        for (int j = 0; j < 8; ++j) red[j][wave] = cv[j];
    __syncthreads();
    if (tid == 0) {
        const float b2v = b2[0];
        for (int j = 0; j < 8; ++j) raw[tok0 + j] = red[j][0] + red[j][1] + b2v;
    }
}

__device__ __forceinline__ double softplus_d(double x) {
    return (x > 0.0) ? x + log1p(exp(-x)) : log1p(exp(x));
}

__global__ __launch_bounds__(256) void repo_cumsum_kernel(const float* __restrict__ raw,
                                                          float* __restrict__ pos) {
    __shared__ double bufA[256];
    __shared__ double bufB[256];
    const int b = blockIdx.x;
    const int t = threadIdx.x;
    const float* r = raw + (size_t)b * SEQ;

    double loc[8];
    double sum = 0.0;
#pragma unroll
    for (int i = 0; i < 8; ++i) {
        sum += softplus_d((double)r[t * 8 + i]);
        loc[i] = sum;
    }
    bufA[t] = sum;
    __syncthreads();

    double* src = bufA;
    double* dst = bufB;
    for (int off = 1; off < 256; off <<= 1) {
        double v = src[t];
        if (t >= off) v += src[t - off];
        dst[t] = v;
        __syncthreads();
        double* tmp = src; src = dst; dst = tmp;
    }
    const double excl = src[t] - sum;
#pragma unroll
    for (int i = 0; i < 8; ++i)
        pos[(size_t)b * SEQ + t * 8 + i] = (float)(excl + loc[i]);
}

// ---------------------------------------------------------------------------
// cos/sin table [tok][32], fp64 angle math done once per (tok,i)
// ---------------------------------------------------------------------------
__global__ __launch_bounds__(256) void sctab_kernel(const float* __restrict__ pos,
                                                    float* __restrict__ costab,
                                                    float* __restrict__ sintab) {
    const int idx = blockIdx.x * 256 + threadIdx.x;  // < TOKENS*32
    const int tok = idx >> 5, i = idx & 31;
    const double ang = (double)pos[tok] * exp(-(double)i * 0.28782313662425574);
    double sa, ca;
    sincos(ang, &sa, &ca);
    costab[idx] = (float)ca;
    sintab[idx] = (float)sa;
}

// ---------------------------------------------------------------------------
// RoPE on Q (in qkv, stride 3072), via table. Thread = (tok, h, 8-dim part).
// ---------------------------------------------------------------------------
__global__ __launch_bounds__(256) void rope_q_kernel(f16* __restrict__ qkv,
                                                     const float* __restrict__ costab,
                                                     const float* __restrict__ sintab) {
    const int idx = blockIdx.x * 256 + threadIdx.x;  // < TOKENS*HEADS*4
    const int part = idx & 3, h = (idx >> 2) & (HEADS - 1), tok = idx >> 6;
    f16* qrow = qkv + (size_t)tok * 3072 + h * HEAD_DIM;
    f16x8 lo = *(const f16x8*)(qrow + part * 8);
    f16x8 hi = *(const f16x8*)(qrow + part * 8 + 32);
    float cs[8], sn[8];
    *(float4*)cs       = *(const float4*)(costab + tok * 32 + part * 8);
    *(float4*)(cs + 4) = *(const float4*)(costab + tok * 32 + part * 8 + 4);
    *(float4*)sn       = *(const float4*)(sintab + tok * 32 + part * 8);
    *(float4*)(sn + 4) = *(const float4*)(sintab + tok * 32 + part * 8 + 4);
#pragma unroll
    for (int u = 0; u < 8; ++u) {
        const float l = (float)lo[u], hh = (float)hi[u];
        lo[u] = (f16)(l * cs[u] - hh * sn[u]);
        hi[u] = (f16)(l * sn[u] + hh * cs[u]);
    }
    *(f16x8*)(qrow + part * 8) = lo;
    *(f16x8*)(qrow + part * 8 + 32) = hi;
}

// ---------------------------------------------------------------------------
// Pack K (with fused RoPE) and V into MFMA-fragment-major global layouts.
// Block = one (b, h, 64-key chunk).
//   kfrag chunk: [frag(jn*2+half)][lane] f16x8  (8*64*8  = 4096 f16 = 8KB)
//   vfrag chunk: [frag(jd*4+jn)][lane]  f16x4  (16*64*4 = 4096 f16 = 8KB)
// ---------------------------------------------------------------------------
__global__ __launch_bounds__(256) void packkv_kernel(const f16* __restrict__ qkv,
                                                     const float* __restrict__ costab,
                                                     const float* __restrict__ sintab,
                                                     f16* __restrict__ kfo,
                                                     f16* __restrict__ vfo) {
    __shared__ __align__(16) f16 kds[64][72];
    __shared__ __align__(16) f16 vds[64][72];  // dim-major (transposed V)
    const int t = threadIdx.x;
    const int s0 = blockIdx.x * 64;
    const int h = blockIdx.y, b = blockIdx.z;
    const int key = t >> 2, part = t & 3;
    const int tok = b * SEQ + s0 + key;
    {
        // K row + rope
        const f16* krow = qkv + (size_t)tok * 3072 + 1024 + h * HEAD_DIM;
        f16x8 lo = *(const f16x8*)(krow + part * 8);
        f16x8 hi = *(const f16x8*)(krow + part * 8 + 32);
        float cs[8], sn[8];
        *(float4*)cs       = *(const float4*)(costab + tok * 32 + part * 8);
        *(float4*)(cs + 4) = *(const float4*)(costab + tok * 32 + part * 8 + 4);
        *(float4*)sn       = *(const float4*)(sintab + tok * 32 + part * 8);
        *(float4*)(sn + 4) = *(const float4*)(sintab + tok * 32 + part * 8 + 4);
#pragma unroll
        for (int u = 0; u < 8; ++u) {
            const float l = (float)lo[u], hh = (float)hi[u];
            kds[key][part * 8 + u]      = (f16)(l * cs[u] - hh * sn[u]);
            kds[key][32 + part * 8 + u] = (f16)(l * sn[u] + hh * cs[u]);
        }
        // V row -> transposed LDS
        const f16* vrow = qkv + (size_t)tok * 3072 + 2048 + h * HEAD_DIM;
        f16x8 v0 = *(const f16x8*)(vrow + part * 16);
        f16x8 v1 = *(const f16x8*)(vrow + part * 16 + 8);
#pragma unroll
        for (int u = 0; u < 8; ++u) {
            vds[part * 16 + u][key] = v0[u];
            vds[part * 16 + 8 + u][key] = v1[u];
        }
    }
    __syncthreads();
    const size_t cb = ((size_t)((b * HEADS + h) * 32) + blockIdx.x) * 4096;
#pragma unroll
    for (int p = 0; p < 2; ++p) {
        const int idx = p * 256 + t;
        const int frag = idx >> 6, lane = idx & 63;
        const int jn = frag >> 1, half = frag & 1, g = lane >> 4, c = lane & 15;
        *(f16x8*)(kfo + cb + frag * 512 + lane * 8) =
            *(const f16x8*)(&kds[jn * 16 + c][half * 32 + g * 8]);
    }
#pragma unroll
    for (int p = 0; p < 4; ++p) {
        const int idx = p * 256 + t;
        const int frag = idx >> 6, lane = idx & 63;
        const int jd = frag >> 2, jn = frag & 3, g = lane >> 4, c = lane & 15;
        *(f16x4*)(vfo + cb + frag * 256 + lane * 4) =
            *(const f16x4*)(&vds[jd * 16 + c][jn * 16 + 4 * g]);
    }
}

// ---------------------------------------------------------------------------
// MFMA flash attention, f16, fragment-major K/V, register double-buffered.
// 4 waves x 32 q-rows per block; role-swapped QK^T; P stays in registers;
// fixed-shift softmax; denominators via ones-MFMA. grid (16,16,2).
// ---------------------------------------------------------------------------
__global__ __launch_bounds__(256, 2) void attn_f16(const f16* __restrict__ qkv,
                                                   const f16* __restrict__ kfr,
                                                   const f16* __restrict__ vfr,
                                                   f16* __restrict__ ao) {
    __shared__ __align__(16) f16 ot[4][32][72];
    const int tid = threadIdx.x;
    const int w = tid >> 6, lane = tid & 63;
    const int g = lane >> 4, c = lane & 15;
    const int h = blockIdx.y, b = blockIdx.z;
    const int row0 = blockIdx.x * 128 + w * 32;

    const f16* qb = qkv + (size_t)(b * SEQ + row0) * 3072 + h * HEAD_DIM + g * 8;
    const f16* kfb = kfr + (size_t)((b * HEADS + h) * 32) * 4096;
    const f16* vfb = vfr + (size_t)((b * HEADS + h) * 32) * 4096;

    f16x8 qf[2][2];
#pragma unroll
    for (int i = 0; i < 2; ++i) {
        qf[i][0] = *(const f16x8*)(qb + (size_t)(i * 16 + c) * 3072);
        qf[i][1] = *(const f16x8*)(qb + (size_t)(i * 16 + c) * 3072 + 32);
    }
    const f32x4 z = {0.f, 0.f, 0.f, 0.f};
    f32x4 acc[4][2];   // [jd][i] of O^T
    f32x4 accl[2];
#pragma unroll
    for (int jd = 0; jd < 4; ++jd) { acc[jd][0] = z; acc[jd][1] = z; }
    accl[0] = z; accl[1] = z;

    const f16x4 ones = {(f16)1.f, (f16)1.f, (f16)1.f, (f16)1.f};
    const float SC = 0.125f * 1.4426950408889634f;

    auto loadfr = [&](int ch, f16x8* kf, f16x4* vf) {
        const f16* kp = kfb + (size_t)ch * 4096 + lane * 8;
#pragma unroll
        for (int f = 0; f < 8; ++f) kf[f] = *(const f16x8*)(kp + f * 512);
        const f16* vp = vfb + (size_t)ch * 4096 + lane * 4;
#pragma unroll
        for (int f = 0; f < 16; ++f) vf[f] = *(const f16x4*)(vp + f * 256);
    };
    auto step = [&](const f16x8* kf, const f16x4* vf) {
#pragma unroll
        for (int i = 0; i < 2; ++i) {
            f32x4 s[4];
#pragma unroll
            for (int jn = 0; jn < 4; ++jn) {
                s[jn] = __builtin_amdgcn_mfma_f32_16x16x32_f16(kf[jn * 2], qf[i][0], z, 0, 0, 0);
                s[jn] = __builtin_amdgcn_mfma_f32_16x16x32_f16(kf[jn * 2 + 1], qf[i][1], s[jn], 0, 0, 0);
            }
#pragma unroll
            for (int jn = 0; jn < 4; ++jn) {
                f16x4 pf;
#pragma unroll
                for (int r = 0; r < 4; ++r)
                    pf[r] = (f16)__builtin_amdgcn_exp2f(fmaf(s[jn][r], SC, -8.0f));
                accl[i] = __builtin_amdgcn_mfma_f32_16x16x16f16(ones, pf, accl[i], 0, 0, 0);
#pragma unroll
                for (int jd = 0; jd < 4; ++jd)
                    acc[jd][i] = __builtin_amdgcn_mfma_f32_16x16x16f16(vf[jd * 4 + jn], pf, acc[jd][i], 0, 0, 0);
            }
        }
    };

    f16x8 kA[8], kB[8];
    f16x4 vA[16], vB[16];
    loadfr(0, kA, vA);
    for (int ch = 0; ch < 32; ch += 2) {
        loadfr(ch + 1, kB, vB);
        step(kA, vA);
        loadfr((ch + 2) & 31, kA, vA);  // wraps on last iter (loaded, unused)
        step(kB, vB);
    }

    // epilogue: O^T in regs -> wave-private LDS transpose -> coalesced store
#pragma unroll
    for (int i = 0; i < 2; ++i) {
        const float inv = 1.0f / accl[i][0];
#pragma unroll
        for (int jd = 0; jd < 4; ++jd)
#pragma unroll
            for (int r = 0; r < 4; ++r)
                ot[w][i * 16 + c][jd * 16 + 4 * g + r] = (f16)(acc[jd][i][r] * inv);
    }
    const int tr = lane >> 1, hf = lane & 1;
    f16* aob = ao + (size_t)(b * SEQ + row0 + tr) * HIDDEN + h * HEAD_DIM + hf * 32;
#pragma unroll
    for (int q = 0; q < 4; ++q)
        *(f16x8*)(aob + q * 8) = *(const f16x8*)(&ot[w][tr][hf * 32 + q * 8]);
}

// ---------------------------------------------------------------------------
// launch
// ---------------------------------------------------------------------------
extern "C" void kernel_launch(void* const* d_in, const int* in_sizes, int n_in,
                              void* d_out, int out_size, void* d_ws, size_t ws_size,
                              hipStream_t stream) {
    const float* x   = (const float*)d_in[0];
    const float* W_q = (const float*)d_in[1];
    const float* W_k = (const float*)d_in[2];
    const float* W_v = (const float*)d_in[3];
    const float* W_o = (const float*)d_in[4];
    const float* rW1 = (const float*)d_in[5];
    const float* rb1 = (const float*)d_in[6];
    const float* rW2 = (const float*)d_in[7];
    const float* rb2 = (const float*)d_in[8];
    float* out = (float*)d_out;

    const size_t MAT = (size_t)TOKENS * HIDDEN;   // 4M
    const size_t WSZ = (size_t)HIDDEN * HIDDEN;   // 1M
    f16* x16  = (f16*)d_ws;
    f16* wqkv = x16 + MAT;            // [3072][1024]
    f16* wot  = wqkv + 3 * WSZ;
    f16* qkv  = wot + WSZ;            // [4096][3072]
    f16* kfr  = qkv + 3 * MAT;        // 4M (fragment-major K)
    f16* vfr  = kfr + MAT;            // 4M (fragment-major V)
    f16* aof  = vfr + MAT;            // 4M
    float* raw    = (float*)(aof + MAT);
    float* pos    = raw + TOKENS;
    float* costab = pos + TOKENS;     // [4096][32]
    float* sintab = costab + TOKENS * 32;

    cast_x_kernel<<<MAT / 2048, 256, 0, stream>>>(x, x16);
    cast_wt_kernel<<<dim3(32, 32), 256, 0, stream>>>(W_q, wqkv);
    cast_wt_kernel<<<dim3(32, 32), 256, 0, stream>>>(W_k, wqkv + WSZ);
    cast_wt_kernel<<<dim3(32, 32), 256, 0, stream>>>(W_v, wqkv + 2 * WSZ);
    cast_wt_kernel<<<dim3(32, 32), 256, 0, stream>>>(W_o, wot);

    gemm_lds<<<dim3(24, 32), 256, 0, stream>>>(x16, wqkv, qkv, nullptr, 3072, 1);

    repo_raw_kernel<<<TOKENS / 8, 128, 0, stream>>>(x, rW1, rb1, rW2, rb2, raw);
    repo_cumsum_kernel<<<BATCH, 256, 0, stream>>>(raw, pos);
    sctab_kernel<<<TOKENS * 32 / 256, 256, 0, stream>>>(pos, costab, sintab);

    rope_q_kernel<<<TOKENS * HEADS * 4 / 256, 256, 0, stream>>>(qkv, costab, sintab);
    packkv_kernel<<<dim3(SEQ / 64, HEADS, BATCH), 256, 0, stream>>>(qkv, costab, sintab, kfr, vfr);

    attn_f16<<<dim3(SEQ / 128, HEADS, BATCH), 256, 0, stream>>>(qkv, kfr, vfr, aof);

    gemm_lds<<<dim3(8, 32), 256, 0, stream>>>(aof, wot, nullptr, out, 1024, 0);
}

// Round 5
// 276.188 us; speedup vs baseline: 1.7521x; 1.0539x over previous
//
#include <hip/hip_runtime.h>
#include <hip/hip_bf16.h>
#include <math.h>

#define HIDDEN 1024
#define HEADS 16
#define HEAD_DIM 64
#define POS_DIM 128
#define BATCH 2
#define SEQ 2048
#define TOKENS (BATCH * SEQ)

typedef _Float16 f16;
typedef __attribute__((ext_vector_type(8))) _Float16 f16x8;
typedef __attribute__((ext_vector_type(4))) _Float16 f16x4;
typedef __attribute__((ext_vector_type(4))) float f32x4;

// ---------------------------------------------------------------------------
// cast x (fp32 -> f16), 8 elems/thread
// ---------------------------------------------------------------------------
__global__ __launch_bounds__(256) void cast_x_kernel(const float* __restrict__ x,
                                                     f16* __restrict__ o) {
    const int i = (blockIdx.x * 256 + threadIdx.x) * 8;
    const float4 u = *(const float4*)(x + i);
    const float4 v = *(const float4*)(x + i + 4);
    f16x8 r = {(f16)u.x, (f16)u.y, (f16)u.z, (f16)u.w,
               (f16)v.x, (f16)v.y, (f16)v.z, (f16)v.w};
    *(f16x8*)(o + i) = r;
}

// ---------------------------------------------------------------------------
// W [1024][1024] fp32 -> Wt [1024][1024] f16 (transpose), 32x32 tiles
// ---------------------------------------------------------------------------
__global__ __launch_bounds__(256) void cast_wt_kernel(const float* __restrict__ W,
                                                      f16* __restrict__ Wt) {
    __shared__ float ts[32][33];
    const int t = threadIdx.x;
    const int k0 = blockIdx.y * 32, n0 = blockIdx.x * 32;
    {
        const int r = t >> 3, c4 = (t & 7) * 4;
        const float4 u = *(const float4*)(W + (size_t)(k0 + r) * HIDDEN + n0 + c4);
        ts[r][c4 + 0] = u.x; ts[r][c4 + 1] = u.y; ts[r][c4 + 2] = u.z; ts[r][c4 + 3] = u.w;
    }
    __syncthreads();
    {
        const int r = t >> 3, c4 = (t & 7) * 4;
        f16* o = Wt + (size_t)(n0 + r) * HIDDEN + k0 + c4;
        o[0] = (f16)ts[c4 + 0][r]; o[1] = (f16)ts[c4 + 1][r];
        o[2] = (f16)ts[c4 + 2][r]; o[3] = (f16)ts[c4 + 3][r];
    }
}

// ---------------------------------------------------------------------------
// W1 [1024][128] fp32 -> w1t_hi/lo [128][1024] f16 split (transpose)
// ---------------------------------------------------------------------------
__global__ __launch_bounds__(256) void cast_w1t_kernel(const float* __restrict__ W1,
                                                       f16* __restrict__ Wh,
                                                       f16* __restrict__ Wl) {
    __shared__ float ts[32][33];
    const int t = threadIdx.x;
    const int k0 = blockIdx.y * 32, p0 = blockIdx.x * 32;
    {
        const int r = t >> 3, c4 = (t & 7) * 4;
        const float4 u = *(const float4*)(W1 + (size_t)(k0 + r) * POS_DIM + p0 + c4);
        ts[r][c4 + 0] = u.x; ts[r][c4 + 1] = u.y; ts[r][c4 + 2] = u.z; ts[r][c4 + 3] = u.w;
    }
    __syncthreads();
    {
        const int r = t >> 3, c4 = (t & 7) * 4;
        f16* oh = Wh + (size_t)(p0 + r) * HIDDEN + k0 + c4;
        f16* ol = Wl + (size_t)(p0 + r) * HIDDEN + k0 + c4;
#pragma unroll
        for (int u = 0; u < 4; ++u) {
            const float v = ts[c4 + u][r];
            const f16 hi = (f16)v;
            oh[u] = hi;
            ol[u] = (f16)(v - (float)hi);
        }
    }
}

// ---------------------------------------------------------------------------
// LDS-staged f16 MFMA GEMM: C[4096][N] = A[4096][1024] @ Bt[N][1024]^T.
// 128x128 block tile, BK=32, 4 waves 2x2 (64x64 each). XOR-swizzled LDS
// (2-way max conflicts), register prefetch of next K-slab.
// ---------------------------------------------------------------------------
__global__ __launch_bounds__(256, 2) void gemm_lds(const f16* __restrict__ A,
                                                   const f16* __restrict__ Bt,
                                                   f16* __restrict__ Cb,
                                                   float* __restrict__ Cf,
                                                   int N, int f16out) {
    __shared__ __align__(16) f16 As[128 * 32];
    __shared__ __align__(16) f16 Bs[128 * 32];
    const int tid = threadIdx.x;
    const int w = tid >> 6, lane = tid & 63;
    const int g = lane >> 4, c = lane & 15;
    const int m0 = blockIdx.y * 128, n0 = blockIdx.x * 128;
    const int wm = (w & 1) * 64, wn = (w >> 1) * 64;

    const int srow = tid >> 2, sseg = tid & 3;
    const int slot = (sseg ^ ((srow ^ (srow >> 2)) & 3)) << 3;
    const f16* gA = A + (size_t)(m0 + srow) * 1024 + sseg * 8;
    const f16* gB = Bt + (size_t)(n0 + srow) * 1024 + sseg * 8;
    f16* sA0 = &As[srow * 32 + slot];
    f16* sA1 = &As[(srow + 64) * 32 + slot];
    f16* sB0 = &Bs[srow * 32 + slot];
    f16* sB1 = &Bs[(srow + 64) * 32 + slot];

    const int foff = ((g ^ ((c ^ (c >> 2)) & 3)) << 3);

    f32x4 acc[4][4];
    const f32x4 z = {0.f, 0.f, 0.f, 0.f};
#pragma unroll
    for (int i = 0; i < 4; ++i)
#pragma unroll
        for (int j = 0; j < 4; ++j) acc[i][j] = z;

    f16x8 pA0 = *(const f16x8*)gA;
    f16x8 pA1 = *(const f16x8*)(gA + 64 * 1024);
    f16x8 pB0 = *(const f16x8*)gB;
    f16x8 pB1 = *(const f16x8*)(gB + 64 * 1024);

    for (int k0 = 0; k0 < 1024; k0 += 32) {
        __syncthreads();
        *(f16x8*)sA0 = pA0; *(f16x8*)sA1 = pA1;
        *(f16x8*)sB0 = pB0; *(f16x8*)sB1 = pB1;
        __syncthreads();
        if (k0 + 32 < 1024) {
            pA0 = *(const f16x8*)(gA + k0 + 32);
            pA1 = *(const f16x8*)(gA + 64 * 1024 + k0 + 32);
            pB0 = *(const f16x8*)(gB + k0 + 32);
            pB1 = *(const f16x8*)(gB + 64 * 1024 + k0 + 32);
        }
        f16x8 af[4], bf[4];
#pragma unroll
        for (int i = 0; i < 4; ++i)
            af[i] = *(const f16x8*)&As[(wm + i * 16 + c) * 32 + foff];
#pragma unroll
        for (int j = 0; j < 4; ++j)
            bf[j] = *(const f16x8*)&Bs[(wn + j * 16 + c) * 32 + foff];
#pragma unroll
        for (int i = 0; i < 4; ++i)
#pragma unroll
            for (int j = 0; j < 4; ++j)
                acc[i][j] = __builtin_amdgcn_mfma_f32_16x16x32_f16(af[i], bf[j], acc[i][j], 0, 0, 0);
    }
#pragma unroll
    for (int i = 0; i < 4; ++i)
#pragma unroll
        for (int j = 0; j < 4; ++j)
#pragma unroll
            for (int r = 0; r < 4; ++r) {
                const size_t off = (size_t)(m0 + wm + i * 16 + 4 * g + r) * N + n0 + wn + j * 16 + c;
                if (f16out) Cb[off] = (f16)acc[i][j][r];
                else Cf[off] = acc[i][j][r];
            }
}

// ---------------------------------------------------------------------------
// RePo MLP via split-f16 MFMA (hi*hi + hi*lo + lo*hi ~ fp32 accuracy).
// Block: 64 tokens, N=128 across 4 waves (32 cols each), K=1024, BK=32.
// Fused epilogue: gelu_tanh(h+b1) @ W2 + b2 -> raw. Grid = 64 blocks.
// ---------------------------------------------------------------------------
__device__ __forceinline__ float gelu_tanh(float x) {
    const float kA = 0.7978845608028654f;
    return 0.5f * x * (1.0f + tanhf(kA * (x + 0.044715f * x * x * x)));
}

__global__ __launch_bounds__(256, 2) void repo_mfma(const float* __restrict__ x,
                                                    const f16* __restrict__ w1h,
                                                    const f16* __restrict__ w1l,
                                                    const float* __restrict__ b1,
                                                    const float* __restrict__ W2,
                                                    const float* __restrict__ b2,
                                                    float* __restrict__ raw) {
    __shared__ __align__(16) f16 Ash[64 * 32], Asl[64 * 32];
    __shared__ __align__(16) f16 Bsh[128 * 32], Bsl[128 * 32];
    __shared__ float red[4][64];
    const int tid = threadIdx.x;
    const int w = tid >> 6, lane = tid & 63;
    const int g = lane >> 4, c = lane & 15;
    const int m0 = blockIdx.x * 64;

    const int arow = tid >> 2, aseg = tid & 3;
    const int aslot = (aseg ^ ((arow ^ (arow >> 2)) & 3)) << 3;
    const float* gA = x + (size_t)(m0 + arow) * 1024 + aseg * 8;
    const f16* gBh0 = w1h + (size_t)arow * 1024 + aseg * 8;
    const f16* gBh1 = w1h + (size_t)(arow + 64) * 1024 + aseg * 8;
    const f16* gBl0 = w1l + (size_t)arow * 1024 + aseg * 8;
    const f16* gBl1 = w1l + (size_t)(arow + 64) * 1024 + aseg * 8;
    f16* sAh = &Ash[arow * 32 + aslot];
    f16* sAl = &Asl[arow * 32 + aslot];
    f16* sBh0 = &Bsh[arow * 32 + aslot];
    f16* sBh1 = &Bsh[(arow + 64) * 32 + aslot];
    f16* sBl0 = &Bsl[arow * 32 + aslot];
    f16* sBl1 = &Bsl[(arow + 64) * 32 + aslot];

    const int foff = ((g ^ ((c ^ (c >> 2)) & 3)) << 3);

    f32x4 acc[4][2];
    const f32x4 z = {0.f, 0.f, 0.f, 0.f};
#pragma unroll
    for (int i = 0; i < 4; ++i) { acc[i][0] = z; acc[i][1] = z; }

    float4 pa0 = *(const float4*)gA;
    float4 pa1 = *(const float4*)(gA + 4);
    f16x8 pbh0 = *(const f16x8*)gBh0, pbh1 = *(const f16x8*)gBh1;
    f16x8 pbl0 = *(const f16x8*)gBl0, pbl1 = *(const f16x8*)gBl1;

    for (int k0 = 0; k0 < 1024; k0 += 32) {
        __syncthreads();
        {
            const float av[8] = {pa0.x, pa0.y, pa0.z, pa0.w, pa1.x, pa1.y, pa1.z, pa1.w};
            f16x8 ah, al;
#pragma unroll
            for (int u = 0; u < 8; ++u) {
                const f16 hi = (f16)av[u];
                ah[u] = hi;
                al[u] = (f16)(av[u] - (float)hi);
            }
            *(f16x8*)sAh = ah; *(f16x8*)sAl = al;
            *(f16x8*)sBh0 = pbh0; *(f16x8*)sBh1 = pbh1;
            *(f16x8*)sBl0 = pbl0; *(f16x8*)sBl1 = pbl1;
        }
        __syncthreads();
        if (k0 + 32 < 1024) {
            pa0 = *(const float4*)(gA + k0 + 32);
            pa1 = *(const float4*)(gA + k0 + 36);
            pbh0 = *(const f16x8*)(gBh0 + k0 + 32);
            pbh1 = *(const f16x8*)(gBh1 + k0 + 32);
            pbl0 = *(const f16x8*)(gBl0 + k0 + 32);
            pbl1 = *(const f16x8*)(gBl1 + k0 + 32);
        }
        f16x8 ah[4], al[4], bh[2], bl[2];
#pragma unroll
        for (int i = 0; i < 4; ++i) {
            ah[i] = *(const f16x8*)&Ash[(i * 16 + c) * 32 + foff];
            al[i] = *(const f16x8*)&Asl[(i * 16 + c) * 32 + foff];
        }
#pragma unroll
        for (int j = 0; j < 2; ++j) {
            bh[j] = *(const f16x8*)&Bsh[(w * 32 + j * 16 + c) * 32 + foff];
            bl[j] = *(const f16x8*)&Bsl[(w * 32 + j * 16 + c) * 32 + foff];
        }
#pragma unroll
        for (int i = 0; i < 4; ++i)
#pragma unroll
            for (int j = 0; j < 2; ++j) {
                acc[i][j] = __builtin_amdgcn_mfma_f32_16x16x32_f16(ah[i], bh[j], acc[i][j], 0, 0, 0);
                acc[i][j] = __builtin_amdgcn_mfma_f32_16x16x32_f16(ah[i], bl[j], acc[i][j], 0, 0, 0);
                acc[i][j] = __builtin_amdgcn_mfma_f32_16x16x32_f16(al[i], bh[j], acc[i][j], 0, 0, 0);
            }
    }
    // epilogue: gelu(h + b1) * W2, reduce over this wave's 32 cols
    float b1v[2], w2v[2];
#pragma unroll
    for (int j = 0; j < 2; ++j) {
        const int col = w * 32 + j * 16 + c;
        b1v[j] = b1[col];
        w2v[j] = W2[col];
    }
    float part[4][4];
#pragma unroll
    for (int i = 0; i < 4; ++i)
#pragma unroll
        for (int r = 0; r < 4; ++r) {
            float s = 0.f;
#pragma unroll
            for (int j = 0; j < 2; ++j)
                s += gelu_tanh(acc[i][j][r] + b1v[j]) * w2v[j];
            s += __shfl_xor(s, 1, 64);
            s += __shfl_xor(s, 2, 64);
            s += __shfl_xor(s, 4, 64);
            s += __shfl_xor(s, 8, 64);
            part[i][r] = s;
        }
    if (c == 0)
#pragma unroll
        for (int i = 0; i < 4; ++i)
#pragma unroll
            for (int r = 0; r < 4; ++r)
                red[w][i * 16 + 4 * g + r] = part[i][r];
    __syncthreads();
    if (tid < 64)
        raw[m0 + tid] = red[0][tid] + red[1][tid] + red[2][tid] + red[3][tid] + b2[0];
}

__device__ __forceinline__ double softplus_d(double x) {
    return (x > 0.0) ? x + log1p(exp(-x)) : log1p(exp(x));
}

__global__ __launch_bounds__(256) void repo_cumsum_kernel(const float* __restrict__ raw,
                                                          float* __restrict__ pos) {
    __shared__ double bufA[256];
    __shared__ double bufB[256];
    const int b = blockIdx.x;
    const int t = threadIdx.x;
    const float* r = raw + (size_t)b * SEQ;

    double loc[8];
    double sum = 0.0;
#pragma unroll
    for (int i = 0; i < 8; ++i) {
        sum += softplus_d((double)r[t * 8 + i]);
        loc[i] = sum;
    }
    bufA[t] = sum;
    __syncthreads();

    double* src = bufA;
    double* dst = bufB;
    for (int off = 1; off < 256; off <<= 1) {
        double v = src[t];
        if (t >= off) v += src[t - off];
        dst[t] = v;
        __syncthreads();
        double* tmp = src; src = dst; dst = tmp;
    }
    const double excl = src[t] - sum;
#pragma unroll
    for (int i = 0; i < 8; ++i)
        pos[(size_t)b * SEQ + t * 8 + i] = (float)(excl + loc[i]);
}

// ---------------------------------------------------------------------------
// cos/sin table [tok][32], fp64 angle math done once per (tok,i)
// ---------------------------------------------------------------------------
__global__ __launch_bounds__(256) void sctab_kernel(const float* __restrict__ pos,
                                                    float* __restrict__ costab,
                                                    float* __restrict__ sintab) {
    const int idx = blockIdx.x * 256 + threadIdx.x;
    const int tok = idx >> 5, i = idx & 31;
    const double ang = (double)pos[tok] * exp(-(double)i * 0.28782313662425574);
    double sa, ca;
    sincos(ang, &sa, &ca);
    costab[idx] = (float)ca;
    sintab[idx] = (float)sa;
}

// ---------------------------------------------------------------------------
// RoPE on Q (in qkv, stride 3072), via table. Thread = (tok, h, 8-dim part).
// ---------------------------------------------------------------------------
__global__ __launch_bounds__(256) void rope_q_kernel(f16* __restrict__ qkv,
                                                     const float* __restrict__ costab,
                                                     const float* __restrict__ sintab) {
    const int idx = blockIdx.x * 256 + threadIdx.x;
    const int part = idx & 3, h = (idx >> 2) & (HEADS - 1), tok = idx >> 6;
    f16* qrow = qkv + (size_t)tok * 3072 + h * HEAD_DIM;
    f16x8 lo = *(const f16x8*)(qrow + part * 8);
    f16x8 hi = *(const f16x8*)(qrow + part * 8 + 32);
    float cs[8], sn[8];
    *(float4*)cs       = *(const float4*)(costab + tok * 32 + part * 8);
    *(float4*)(cs + 4) = *(const float4*)(costab + tok * 32 + part * 8 + 4);
    *(float4*)sn       = *(const float4*)(sintab + tok * 32 + part * 8);
    *(float4*)(sn + 4) = *(const float4*)(sintab + tok * 32 + part * 8 + 4);
#pragma unroll
    for (int u = 0; u < 8; ++u) {
        const float l = (float)lo[u], hh = (float)hi[u];
        lo[u] = (f16)(l * cs[u] - hh * sn[u]);
        hi[u] = (f16)(l * sn[u] + hh * cs[u]);
    }
    *(f16x8*)(qrow + part * 8) = lo;
    *(f16x8*)(qrow + part * 8 + 32) = hi;
}

// ---------------------------------------------------------------------------
// Pack K (with fused RoPE) and V into MFMA-fragment-major global layouts.
// ---------------------------------------------------------------------------
__global__ __launch_bounds__(256) void packkv_kernel(const f16* __restrict__ qkv,
                                                     const float* __restrict__ costab,
                                                     const float* __restrict__ sintab,
                                                     f16* __restrict__ kfo,
                                                     f16* __restrict__ vfo) {
    __shared__ __align__(16) f16 kds[64][72];
    __shared__ __align__(16) f16 vds[64][72];
    const int t = threadIdx.x;
    const int s0 = blockIdx.x * 64;
    const int h = blockIdx.y, b = blockIdx.z;
    const int key = t >> 2, part = t & 3;
    const int tok = b * SEQ + s0 + key;
    {
        const f16* krow = qkv + (size_t)tok * 3072 + 1024 + h * HEAD_DIM;
        f16x8 lo = *(const f16x8*)(krow + part * 8);
        f16x8 hi = *(const f16x8*)(krow + part * 8 + 32);
        float cs[8], sn[8];
        *(float4*)cs       = *(const float4*)(costab + tok * 32 + part * 8);
        *(float4*)(cs + 4) = *(const float4*)(costab + tok * 32 + part * 8 + 4);
        *(float4*)sn       = *(const float4*)(sintab + tok * 32 + part * 8);
        *(float4*)(sn + 4) = *(const float4*)(sintab + tok * 32 + part * 8 + 4);
#pragma unroll
        for (int u = 0; u < 8; ++u) {
            const float l = (float)lo[u], hh = (float)hi[u];
            kds[key][part * 8 + u]      = (f16)(l * cs[u] - hh * sn[u]);
            kds[key][32 + part * 8 + u] = (f16)(l * sn[u] + hh * cs[u]);
        }
        const f16* vrow = qkv + (size_t)tok * 3072 + 2048 + h * HEAD_DIM;
        f16x8 v0 = *(const f16x8*)(vrow + part * 16);
        f16x8 v1 = *(const f16x8*)(vrow + part * 16 + 8);
#pragma unroll
        for (int u = 0; u < 8; ++u) {
            vds[part * 16 + u][key] = v0[u];
            vds[part * 16 + 8 + u][key] = v1[u];
        }
    }
    __syncthreads();
    const size_t cb = ((size_t)((b * HEADS + h) * 32) + blockIdx.x) * 4096;
#pragma unroll
    for (int p = 0; p < 2; ++p) {
        const int idx = p * 256 + t;
        const int frag = idx >> 6, lane = idx & 63;
        const int jn = frag >> 1, half = frag & 1, g = lane >> 4, c = lane & 15;
        *(f16x8*)(kfo + cb + frag * 512 + lane * 8) =
            *(const f16x8*)(&kds[jn * 16 + c][half * 32 + g * 8]);
    }
#pragma unroll
    for (int p = 0; p < 4; ++p) {
        const int idx = p * 256 + t;
        const int frag = idx >> 6, lane = idx & 63;
        const int jd = frag >> 2, jn = frag & 3, g = lane >> 4, c = lane & 15;
        *(f16x4*)(vfo + cb + frag * 256 + lane * 4) =
            *(const f16x4*)(&vds[jd * 16 + c][jn * 16 + 4 * g]);
    }
}

// ---------------------------------------------------------------------------
// MFMA flash attention, f16, fragment-major K/V, register double-buffered.
// ---------------------------------------------------------------------------
__global__ __launch_bounds__(256, 2) void attn_f16(const f16* __restrict__ qkv,
                                                   const f16* __restrict__ kfr,
                                                   const f16* __restrict__ vfr,
                                                   f16* __restrict__ ao) {
    __shared__ __align__(16) f16 ot[4][32][72];
    const int tid = threadIdx.x;
    const int w = tid >> 6, lane = tid & 63;
    const int g = lane >> 4, c = lane & 15;
    const int h = blockIdx.y, b = blockIdx.z;
    const int row0 = blockIdx.x * 128 + w * 32;

    const f16* qb = qkv + (size_t)(b * SEQ + row0) * 3072 + h * HEAD_DIM + g * 8;
    const f16* kfb = kfr + (size_t)((b * HEADS + h) * 32) * 4096;
    const f16* vfb = vfr + (size_t)((b * HEADS + h) * 32) * 4096;

    f16x8 qf[2][2];
#pragma unroll
    for (int i = 0; i < 2; ++i) {
        qf[i][0] = *(const f16x8*)(qb + (size_t)(i * 16 + c) * 3072);
        qf[i][1] = *(const f16x8*)(qb + (size_t)(i * 16 + c) * 3072 + 32);
    }
    const f32x4 z = {0.f, 0.f, 0.f, 0.f};
    f32x4 acc[4][2];
    f32x4 accl[2];
#pragma unroll
    for (int jd = 0; jd < 4; ++jd) { acc[jd][0] = z; acc[jd][1] = z; }
    accl[0] = z; accl[1] = z;

    const f16x4 ones = {(f16)1.f, (f16)1.f, (f16)1.f, (f16)1.f};
    const float SC = 0.125f * 1.4426950408889634f;

    auto loadfr = [&](int ch, f16x8* kf, f16x4* vf) {
        const f16* kp = kfb + (size_t)ch * 4096 + lane * 8;
#pragma unroll
        for (int f = 0; f < 8; ++f) kf[f] = *(const f16x8*)(kp + f * 512);
        const f16* vp = vfb + (size_t)ch * 4096 + lane * 4;
#pragma unroll
        for (int f = 0; f < 16; ++f) vf[f] = *(const f16x4*)(vp + f * 256);
    };
    auto step = [&](const f16x8* kf, const f16x4* vf) {
#pragma unroll
        for (int i = 0; i < 2; ++i) {
            f32x4 s[4];
#pragma unroll
            for (int jn = 0; jn < 4; ++jn) {
                s[jn] = __builtin_amdgcn_mfma_f32_16x16x32_f16(kf[jn * 2], qf[i][0], z, 0, 0, 0);
                s[jn] = __builtin_amdgcn_mfma_f32_16x16x32_f16(kf[jn * 2 + 1], qf[i][1], s[jn], 0, 0, 0);
            }
#pragma unroll
            for (int jn = 0; jn < 4; ++jn) {
                f16x4 pf;
#pragma unroll
                for (int r = 0; r < 4; ++r)
                    pf[r] = (f16)__builtin_amdgcn_exp2f(fmaf(s[jn][r], SC, -8.0f));
                accl[i] = __builtin_amdgcn_mfma_f32_16x16x16f16(ones, pf, accl[i], 0, 0, 0);
#pragma unroll
                for (int jd = 0; jd < 4; ++jd)
                    acc[jd][i] = __builtin_amdgcn_mfma_f32_16x16x16f16(vf[jd * 4 + jn], pf, acc[jd][i], 0, 0, 0);
            }
        }
    };

    f16x8 kA[8], kB[8];
    f16x4 vA[16], vB[16];
    loadfr(0, kA, vA);
    for (int ch = 0; ch < 32; ch += 2) {
        loadfr(ch + 1, kB, vB);
        step(kA, vA);
        loadfr((ch + 2) & 31, kA, vA);
        step(kB, vB);
    }

#pragma unroll
    for (int i = 0; i < 2; ++i) {
        const float inv = 1.0f / accl[i][0];
#pragma unroll
        for (int jd = 0; jd < 4; ++jd)
#pragma unroll
            for (int r = 0; r < 4; ++r)
                ot[w][i * 16 + c][jd * 16 + 4 * g + r] = (f16)(acc[jd][i][r] * inv);
    }
    const int tr = lane >> 1, hf = lane & 1;
    f16* aob = ao + (size_t)(b * SEQ + row0 + tr) * HIDDEN + h * HEAD_DIM + hf * 32;
#pragma unroll
    for (int q = 0; q < 4; ++q)
        *(f16x8*)(aob + q * 8) = *(const f16x8*)(&ot[w][tr][hf * 32 + q * 8]);
}

// ---------------------------------------------------------------------------
// launch
// ---------------------------------------------------------------------------
extern "C" void kernel_launch(void* const* d_in, const int* in_sizes, int n_in,
                              void* d_out, int out_size, void* d_ws, size_t ws_size,
                              hipStream_t stream) {
    const float* x   = (const float*)d_in[0];
    const float* W_q = (const float*)d_in[1];
    const float* W_k = (const float*)d_in[2];
    const float* W_v = (const float*)d_in[3];
    const float* W_o = (const float*)d_in[4];
    const float* rW1 = (const float*)d_in[5];
    const float* rb1 = (const float*)d_in[6];
    const float* rW2 = (const float*)d_in[7];
    const float* rb2 = (const float*)d_in[8];
    float* out = (float*)d_out;

    const size_t MAT = (size_t)TOKENS * HIDDEN;   // 4M
    const size_t WSZ = (size_t)HIDDEN * HIDDEN;   // 1M
    f16* x16  = (f16*)d_ws;
    f16* wqkv = x16 + MAT;            // [3072][1024]
    f16* wot  = wqkv + 3 * WSZ;
    f16* qkv  = wot + WSZ;            // [4096][3072]
    f16* kfr  = qkv + 3 * MAT;
    f16* vfr  = kfr + MAT;
    f16* aof  = vfr + MAT;
    f16* w1h  = aof + MAT;            // [128][1024]
    f16* w1l  = w1h + POS_DIM * HIDDEN;
    float* raw    = (float*)(w1l + POS_DIM * HIDDEN);
    float* pos    = raw + TOKENS;
    float* costab = pos + TOKENS;
    float* sintab = costab + TOKENS * 32;

    cast_x_kernel<<<MAT / 2048, 256, 0, stream>>>(x, x16);
    cast_wt_kernel<<<dim3(32, 32), 256, 0, stream>>>(W_q, wqkv);
    cast_wt_kernel<<<dim3(32, 32), 256, 0, stream>>>(W_k, wqkv + WSZ);
    cast_wt_kernel<<<dim3(32, 32), 256, 0, stream>>>(W_v, wqkv + 2 * WSZ);
    cast_wt_kernel<<<dim3(32, 32), 256, 0, stream>>>(W_o, wot);
    cast_w1t_kernel<<<dim3(4, 32), 256, 0, stream>>>(rW1, w1h, w1l);

    gemm_lds<<<dim3(24, 32), 256, 0, stream>>>(x16, wqkv, qkv, nullptr, 3072, 1);

    repo_mfma<<<64, 256, 0, stream>>>(x, w1h, w1l, rb1, rW2, rb2, raw);
    repo_cumsum_kernel<<<BATCH, 256, 0, stream>>>(raw, pos);
    sctab_kernel<<<TOKENS * 32 / 256, 256, 0, stream>>>(pos, costab, sintab);

    rope_q_kernel<<<TOKENS * HEADS * 4 / 256, 256, 0, stream>>>(qkv, costab, sintab);
    packkv_kernel<<<dim3(SEQ / 64, HEADS, BATCH), 256, 0, stream>>>(qkv, costab, sintab, kfr, vfr);

    attn_f16<<<dim3(SEQ / 128, HEADS, BATCH), 256, 0, stream>>>(qkv, kfr, vfr, aof);

    gemm_lds<<<dim3(8, 32), 256, 0, stream>>>(aof, wot, nullptr, out, 1024, 0);
}